// Round 1
// baseline (234.586 us; speedup 1.0000x reference)
//
#include <hip/hip_runtime.h>
#include <hip/hip_bf16.h>

#define NN 8192
#define HH 256
#define EE (NN*32)
#define ALPHAC 0.2f
#define CHUNK 64
#define NCHUNK (NN/CHUNK)   // 128

// workspace layout (float offsets)
#define OFF_WH     0
#define OFF_S      (OFF_WH + NN*HH)
#define OFF_D      (OFF_S + NN)
#define OFF_SORTD  (OFF_D + NN)
#define OFF_PERM   (OFF_SORTD + NN)   /* ints */
#define OFF_EA     (OFF_PERM + NN)
#define OFF_E1     (OFF_EA + NN)
#define OFF_APREF  (OFF_E1 + NN)
#define OFF_BPREF  (OFF_APREF + NN)
#define OFF_APART  (OFF_BPREF + NN)
#define OFF_BPART  (OFF_APART + NN*HH)
#define OFF_CTA    (OFF_BPART + NN*HH)
#define OFF_CTB    (OFF_CTA + NCHUNK*HH)
#define OFF_CPA    (OFF_CTB + NCHUNK*HH)
#define OFF_CPB    (OFF_CPA + (NCHUNK+1)*HH)
#define OFF_DEG    (OFF_CPB + (NCHUNK+1)*HH)
#define OFF_DINV   (OFF_DEG + NN)
#define OFF_WNODE  (OFF_DINV + NN)
#define OFF_V      (OFF_WNODE + NN)
// total = OFF_V + HH = 6,513,408 floats ~ 24.9 MiB

__global__ void k_init(float* ws) {
    int i = blockIdx.x*256 + threadIdx.x;
    if (i < NN) ws[OFF_DEG + i] = 1.0f;          // self-loop contributes 1 to degree
    if (i < HH) ws[OFF_V + i] = 0.0f;
}

// Wh = features[NN,HH] @ W_att[HH,HH]  (f32, 64x64 tile, BK=32, LDS both-transposed-A)
__global__ __launch_bounds__(256) void k_gemm_wh(const float* __restrict__ A,
                                                 const float* __restrict__ B,
                                                 float* __restrict__ C) {
    __shared__ float As[32][68];   // As[k][row]  (transposed for float4 reads)
    __shared__ float Bs[32][68];   // Bs[k][col]
    int tid = threadIdx.x;
    int row0 = blockIdx.x * 64, col0 = blockIdx.y * 64;
    int tx = tid & 15, ty = tid >> 4;
    float acc[4][4] = {};
    int a_r = tid >> 2;           // 0..63
    int a_k = (tid & 3) * 8;      // 0,8,16,24
    int b_k = tid >> 3;           // 0..31
    int b_c = (tid & 7) * 8;      // 0..56
    const float* Aptr = A + (size_t)(row0 + a_r)*HH + a_k;
    const float* Bptr = B + (size_t)b_k*HH + col0 + b_c;
    for (int k0 = 0; k0 < HH; k0 += 32) {
        float4 av0 = *(const float4*)(Aptr + k0);
        float4 av1 = *(const float4*)(Aptr + k0 + 4);
        float4 bv0 = *(const float4*)(Bptr + (size_t)k0*HH);
        float4 bv1 = *(const float4*)(Bptr + (size_t)k0*HH + 4);
        __syncthreads();
        As[a_k+0][a_r] = av0.x; As[a_k+1][a_r] = av0.y;
        As[a_k+2][a_r] = av0.z; As[a_k+3][a_r] = av0.w;
        As[a_k+4][a_r] = av1.x; As[a_k+5][a_r] = av1.y;
        As[a_k+6][a_r] = av1.z; As[a_k+7][a_r] = av1.w;
        *(float4*)&Bs[b_k][b_c]   = bv0;
        *(float4*)&Bs[b_k][b_c+4] = bv1;
        __syncthreads();
        #pragma unroll
        for (int kk = 0; kk < 32; ++kk) {
            float4 ar = *(const float4*)&As[kk][ty*4];
            float4 br = *(const float4*)&Bs[kk][tx*4];
            float a0[4] = {ar.x, ar.y, ar.z, ar.w};
            float b0[4] = {br.x, br.y, br.z, br.w};
            #pragma unroll
            for (int r = 0; r < 4; ++r)
                #pragma unroll
                for (int c = 0; c < 4; ++c)
                    acc[r][c] += a0[r]*b0[c];
        }
    }
    #pragma unroll
    for (int r = 0; r < 4; ++r) {
        float4 o = make_float4(acc[r][0], acc[r][1], acc[r][2], acc[r][3]);
        *(float4*)(C + (size_t)(row0 + ty*4 + r)*HH + col0 + tx*4) = o;
    }
}

// s_i = Wh[i]·a_src, d_i = Wh[i]·a_dst  — one wave per row
__global__ void k_sd(const float* __restrict__ Wh, const float* __restrict__ a_src,
                     const float* __restrict__ a_dst, float* ws) {
    int wave = threadIdx.x >> 6, lane = threadIdx.x & 63;
    int row = blockIdx.x*4 + wave;
    float4 wh = *(const float4*)(Wh + (size_t)row*HH + lane*4);
    float4 as = *(const float4*)(a_src + lane*4);
    float4 ad = *(const float4*)(a_dst + lane*4);
    float ss = wh.x*as.x + wh.y*as.y + wh.z*as.z + wh.w*as.w;
    float dd = wh.x*ad.x + wh.y*ad.y + wh.z*ad.z + wh.w*ad.w;
    #pragma unroll
    for (int off = 32; off; off >>= 1) {
        ss += __shfl_xor(ss, off);
        dd += __shfl_xor(dd, off);
    }
    if (lane == 0) { ws[OFF_S+row] = ss; ws[OFF_D+row] = dd; }
}

// rank each d_j by counting (O(N^2) LDS compares, 4 threads per element)
__global__ __launch_bounds__(256) void k_rank(float* ws) {
    __shared__ float ld[NN];    // 32 KB
    const float* d = ws + OFF_D;
    for (int m = threadIdx.x; m < NN; m += 256) ld[m] = d[m];
    __syncthreads();
    int j   = blockIdx.x*64 + (threadIdx.x >> 2);
    int sub = threadIdx.x & 3;
    float dj = ld[j];
    int cnt = 0;
    int q0 = sub * 2048;
    #pragma unroll 8
    for (int q = q0; q < q0 + 2048; ++q) {
        float dq = ld[q];
        cnt += (dq < dj) || (dq == dj && q < j);
    }
    cnt += __shfl_xor(cnt, 1);
    cnt += __shfl_xor(cnt, 2);
    if (sub == 0) {
        ws[OFF_SORTD + cnt] = dj;
        ((int*)ws)[OFF_PERM + cnt] = j;
        ws[OFF_EA + cnt] = expf(ALPHAC * dj);
        ws[OFF_E1 + cnt] = expf(dj);
    }
}

// inclusive scalar prefix sums of ea, e1 over sorted order (1 block)
__global__ void k_scan_scalar(float* ws) {
    __shared__ float sa[256], sb[256];
    int t = threadIdx.x;
    const float* ea = ws + OFF_EA;
    const float* e1 = ws + OFF_E1;
    int base = t * 32;
    float ta = 0.f, tb = 0.f;
    for (int q = 0; q < 32; ++q) { ta += ea[base+q]; tb += e1[base+q]; }
    sa[t] = ta; sb[t] = tb;
    __syncthreads();
    for (int off = 1; off < 256; off <<= 1) {
        float xa = (t >= off) ? sa[t-off] : 0.f;
        float xb = (t >= off) ? sb[t-off] : 0.f;
        __syncthreads();
        sa[t] += xa; sb[t] += xb;
        __syncthreads();
    }
    float ra = sa[t] - ta, rb = sb[t] - tb;   // exclusive at thread start
    for (int q = 0; q < 32; ++q) {
        ra += ea[base+q]; ws[OFF_APREF+base+q] = ra;
        rb += e1[base+q]; ws[OFF_BPREF+base+q] = rb;
    }
}

// per-chunk inclusive vector prefixes of exp(alpha d)*Wh and exp(d)*Wh (sorted order)
__global__ __launch_bounds__(256) void k_vecpref(float* ws) {
    __shared__ int   sp[CHUNK];
    __shared__ float sea[CHUNK], se1[CHUNK];
    int c = blockIdx.x, h = threadIdx.x;
    int k0 = c * CHUNK;
    if (h < CHUNK) {
        sp[h]  = ((int*)ws)[OFF_PERM + k0 + h];
        sea[h] = ws[OFF_EA + k0 + h];
        se1[h] = ws[OFF_E1 + k0 + h];
    }
    __syncthreads();
    const float* Wh = ws + OFF_WH;
    float acca = 0.f, accb = 0.f;
    for (int kk = 0; kk < CHUNK; ++kk) {
        float w = Wh[(size_t)sp[kk]*HH + h];
        acca += sea[kk]*w; accb += se1[kk]*w;
        ws[OFF_APART + (size_t)(k0+kk)*HH + h] = acca;
        ws[OFF_BPART + (size_t)(k0+kk)*HH + h] = accb;
    }
    ws[OFF_CTA + (size_t)c*HH + h] = acca;
    ws[OFF_CTB + (size_t)c*HH + h] = accb;
}

// exclusive scan of chunk totals (entry NCHUNK = grand total)
__global__ void k_chunkscan(float* ws) {
    int h = threadIdx.x;
    float ra = 0.f, rb = 0.f;
    for (int c = 0; c < NCHUNK; ++c) {
        ws[OFF_CPA + (size_t)c*HH + h] = ra;
        ws[OFF_CPB + (size_t)c*HH + h] = rb;
        ra += ws[OFF_CTA + (size_t)c*HH + h];
        rb += ws[OFF_CTB + (size_t)c*HH + h];
    }
    ws[OFF_CPA + (size_t)NCHUNK*HH + h] = ra;
    ws[OFF_CPB + (size_t)NCHUNK*HH + h] = rb;
}

__global__ void k_deg(const int* __restrict__ ei, float* ws) {
    int e = blockIdx.x*256 + threadIdx.x;
    if (e < EE) atomicAdd(ws + OFF_DEG + ei[e], 1.0f);
}

__global__ void k_dinv(float* ws) {
    int i = blockIdx.x*256 + threadIdx.x;
    if (i < NN) {
        float dv = rsqrtf(ws[OFF_DEG + i]);
        ws[OFF_DINV + i] = dv;
        ws[OFF_WNODE + i] = dv*dv;     // self-loop term
    }
}

__global__ void k_wnode(const int* __restrict__ ei, float* ws) {
    int e = blockIdx.x*256 + threadIdx.x;
    if (e < EE) {
        int r = ei[e], c = ei[EE + e];
        atomicAdd(ws + OFF_WNODE + c, ws[OFF_DINV + r] * ws[OFF_DINV + c]);
    }
}

__device__ __forceinline__ float elu1(float x) {
    return x > 0.f ? x : (expf(x) - 1.f);
}

// per-row attention via prefix lookup; accumulate v = sum_i wnode[i]*h1[i]
__global__ __launch_bounds__(256) void k_rows(float* ws) {
    __shared__ float sd[NN];       // 32 KB sorted d
    __shared__ float red[4][256];  // cross-wave reduction
    int tid = threadIdx.x;
    for (int m = tid; m < NN; m += 256) sd[m] = ws[OFF_SORTD + m];
    __syncthreads();
    int wave = tid >> 6, lane = tid & 63;
    int gw = blockIdx.x*4 + wave;            // 0..1023
    const float* apart = ws + OFF_APART;
    const float* bpart = ws + OFF_BPART;
    const float* cpa = ws + OFF_CPA;
    const float* cpb = ws + OFF_CPB;
    float btot = ws[OFF_BPREF + NN - 1];
    float4 BT = *(const float4*)(cpb + (size_t)NCHUNK*HH + lane*4);
    float accx = 0.f, accy = 0.f, accz = 0.f, accw = 0.f;
    for (int r = 0; r < 8; ++r) {
        int i = gw*8 + r;
        float si = ws[OFF_S + i];
        float t = -si;
        int lo = 0, hi = NN;
        while (lo < hi) {
            int mid = (lo + hi) >> 1;
            if (sd[mid] <= t) lo = mid + 1; else hi = mid;
        }
        int k = lo;    // count of d_j <= -s_i  (negative-branch prefix length)
        float eas = expf(ALPHAC * si), es = expf(si);
        float av = 0.f, bv = 0.f;
        float Ax=0.f, Ay=0.f, Az=0.f, Aw=0.f, Bx=0.f, By=0.f, Bz=0.f, Bw=0.f;
        if (k > 0) {
            int km = k - 1, cc = km >> 6;
            av = ws[OFF_APREF + km]; bv = ws[OFF_BPREF + km];
            float4 pa = *(const float4*)(apart + (size_t)km*HH + lane*4);
            float4 ca = *(const float4*)(cpa + (size_t)cc*HH + lane*4);
            float4 pb = *(const float4*)(bpart + (size_t)km*HH + lane*4);
            float4 cb = *(const float4*)(cpb + (size_t)cc*HH + lane*4);
            Ax = pa.x + ca.x; Ay = pa.y + ca.y; Az = pa.z + ca.z; Aw = pa.w + ca.w;
            Bx = pb.x + cb.x; By = pb.y + cb.y; Bz = pb.z + cb.z; Bw = pb.w + cb.w;
        }
        float Z = eas*av + es*(btot - bv);
        float invZ = 1.f / Z;
        float w = ws[OFF_WNODE + i];
        accx += w * elu1((eas*Ax + es*(BT.x - Bx)) * invZ);
        accy += w * elu1((eas*Ay + es*(BT.y - By)) * invZ);
        accz += w * elu1((eas*Az + es*(BT.z - Bz)) * invZ);
        accw += w * elu1((eas*Aw + es*(BT.w - Bw)) * invZ);
    }
    red[wave][lane*4+0] = accx;
    red[wave][lane*4+1] = accy;
    red[wave][lane*4+2] = accz;
    red[wave][lane*4+3] = accw;
    __syncthreads();
    float sum = red[0][tid] + red[1][tid] + red[2][tid] + red[3][tid];
    atomicAdd(ws + OFF_V + tid, sum);
}

// head: (v @ gcn_w)/N + gcn_b -> @ out_w + out_b -> softmax(2)
__global__ void k_final(const float* __restrict__ gcn_w, const float* __restrict__ gcn_b,
                        const float* __restrict__ out_w, const float* __restrict__ out_b,
                        float* ws, float* out) {
    __shared__ float vl[HH];
    __shared__ float r0s[256], r1s[256];
    int t = threadIdx.x;
    vl[t] = ws[OFF_V + t];
    __syncthreads();
    float acc = 0.f;
    for (int h = 0; h < HH; ++h) acc += vl[h] * gcn_w[(size_t)h*HH + t];
    float meanv = acc * (1.0f/(float)NN) + gcn_b[t];
    r0s[t] = meanv * out_w[t*2+0];
    r1s[t] = meanv * out_w[t*2+1];
    __syncthreads();
    for (int off = 128; off; off >>= 1) {
        if (t < off) { r0s[t] += r0s[t+off]; r1s[t] += r1s[t+off]; }
        __syncthreads();
    }
    if (t == 0) {
        float res0 = r0s[0] + out_b[0], res1 = r1s[0] + out_b[1];
        float m = fmaxf(res0, res1);
        float e0 = expf(res0 - m), e1v = expf(res1 - m);
        float inv = 1.f / (e0 + e1v);
        out[0] = e0 * inv;
        out[1] = e1v * inv;
    }
}

extern "C" void kernel_launch(void* const* d_in, const int* in_sizes, int n_in,
                              void* d_out, int out_size, void* d_ws, size_t ws_size,
                              hipStream_t stream) {
    const float* features = (const float*)d_in[0];
    const int*   eidx     = (const int*)d_in[1];
    const float* W_att    = (const float*)d_in[2];
    const float* a_src    = (const float*)d_in[3];
    const float* a_dst    = (const float*)d_in[4];
    const float* gcn_w    = (const float*)d_in[5];
    const float* gcn_b    = (const float*)d_in[6];
    const float* out_w    = (const float*)d_in[7];
    const float* out_b    = (const float*)d_in[8];
    float* ws  = (float*)d_ws;
    float* out = (float*)d_out;

    k_init<<<NN/256, 256, 0, stream>>>(ws);
    k_gemm_wh<<<dim3(NN/64, HH/64), 256, 0, stream>>>(features, W_att, ws + OFF_WH);
    k_sd<<<NN/4, 256, 0, stream>>>(ws + OFF_WH, a_src, a_dst, ws);
    k_rank<<<NN/64, 256, 0, stream>>>(ws);
    k_scan_scalar<<<1, 256, 0, stream>>>(ws);
    k_vecpref<<<NCHUNK, 256, 0, stream>>>(ws);
    k_chunkscan<<<1, HH, 0, stream>>>(ws);
    k_deg<<<EE/256, 256, 0, stream>>>(eidx, ws);
    k_dinv<<<NN/256, 256, 0, stream>>>(ws);
    k_wnode<<<EE/256, 256, 0, stream>>>(eidx, ws);
    k_rows<<<256, 256, 0, stream>>>(ws);
    k_final<<<1, 256, 0, stream>>>(gcn_w, gcn_b, out_w, out_b, ws, out);
}